// Round 8
// baseline (198.292 us; speedup 1.0000x reference)
//
#include <hip/hip_runtime.h>
#include <hip/hip_bf16.h>
#include <hip/hip_cooperative_groups.h>

namespace cg = cooperative_groups;

#define D_MODEL 1024
#define HEAD    64
#define SEQ     2048
#define BATCH   4
#define ROWS    (BATCH * SEQ)   // 8192

typedef __attribute__((ext_vector_type(8))) short  short8;   // 8 bf16
typedef __attribute__((ext_vector_type(4))) short  short4v;  // 4 bf16
typedef __attribute__((ext_vector_type(4))) float  f32x4;

__device__ __forceinline__ unsigned short f2bf(float f) {
    union { __hip_bfloat16 h; unsigned short u; } c;
    c.h = __float2bfloat16(f);
    return c.u;
}

// ---------------------------------------------------------------------------
// Fused cooperative kernel: grid 256 x 512 thr (1 block/CU).
//  Phase A (blocks 0..47): W[1024][64] f32 -> Wt[192][1024] bf16 transposed.
//  grid.sync()
//  Phase B (all blocks): GEMM C[8192][192] = x.Wt^T + b. BM=32, 8 waves
//    (2 row x 4 col tiles of 16x48), x panel staged once in LDS, B frags
//    from L2-resident Wt with static double-buffered prefetch.
//    Outputs qb bf16 (x0.125), kb bf16, V^T bf16.
//  grid.sync()
//  Phase C (all blocks): causal flash attention (R7 structure, + V prefetch).
//    Block p of 64, batch b = bx>>6; q-tiles {p, 127-p}; 8 waves each owning
//    a 32-kv slice of a 256-kv iteration, independent (m,l,acc), zero
//    barriers in the kv loop; flash-decoding merge per q-tile.
// ---------------------------------------------------------------------------
__global__ __launch_bounds__(512, 2) void fused_all(
    const float* __restrict__ x,
    const float* __restrict__ Wq, const float* __restrict__ bq,
    const float* __restrict__ Wk, const float* __restrict__ bk,
    const float* __restrict__ Wv, const float* __restrict__ bv,
    unsigned short* __restrict__ Wt,
    unsigned short* __restrict__ qb, unsigned short* __restrict__ kb,
    unsigned short* __restrict__ vt, float* __restrict__ out)
{
    __shared__ union SMem {
        struct { float Lw[64][65]; } a;                         // 16.6 KB
        struct { unsigned short Xs[32 * 1032];                  // 64.5 KB
                 float Vx[32][66]; } bp;                        // + 8.25 KB
        struct { unsigned short Qs[16 * 68];                    //  2.2 KB
                 unsigned short Ps[8][16 * 40];                 // 10 KB
                 float Cs[8][16 * 68];                          // 34.8 KB
                 float Sm[128], Sl[128]; } c;                   //  1 KB
    } sm;

    cg::grid_group grid = cg::this_grid();

    const int tid  = threadIdx.x;
    const int bx   = blockIdx.x;
    const int lane = tid & 63;
    const int w    = tid >> 6;        // 0..7
    const int l15  = lane & 15;
    const int g    = lane >> 4;       // 0..3

    // ===================== Phase A: W -> Wt (48 blocks) ====================
    if (bx < 48) {
        const int mat = bx >> 4;
        const int k0  = (bx & 15) * 64;
        const float* W = (mat == 0) ? Wq : (mat == 1 ? Wk : Wv);
        #pragma unroll
        for (int j = 0; j < 2; ++j) {
            const int idx = j * 2048 + tid * 4;          // 0..4095
            const int r = idx >> 6, cc = idx & 63;
            f32x4 v4 = *(const f32x4*)(W + (size_t)(k0 + r) * HEAD + cc);
            sm.a.Lw[r][cc]   = v4[0]; sm.a.Lw[r][cc+1] = v4[1];
            sm.a.Lw[r][cc+2] = v4[2]; sm.a.Lw[r][cc+3] = v4[3];
        }
        __syncthreads();
        const int col = tid >> 3, kc = (tid & 7) * 8;
        short8 o;
        #pragma unroll
        for (int j = 0; j < 8; ++j) o[j] = f2bf(sm.a.Lw[kc + j][col]);
        *(short8*)(Wt + (size_t)(mat * 64 + col) * D_MODEL + k0 + kc) = o;
    }

    grid.sync();

    // ===================== Phase B: QKV GEMM (BM=32) =======================
    {
        const int wr = w & 1, wc = w >> 1;               // row/col wave tile
        const int row0 = bx * 32;

        // ---- stage x panel (32 x 1024) as bf16 ----
        const int xrow  = tid >> 4;                      // 0..31
        const int cbase = (tid & 15) * 4;
        #pragma unroll
        for (int j = 0; j < 16; ++j) {
            const int col = j * 64 + cbase;
            f32x4 v4 = *(const f32x4*)(x + (size_t)(row0 + xrow) * D_MODEL + col);
            short4v pk;
            pk[0] = f2bf(v4[0]); pk[1] = f2bf(v4[1]);
            pk[2] = f2bf(v4[2]); pk[3] = f2bf(v4[3]);
            *(short4v*)&sm.bp.Xs[xrow * 1032 + col] = pk;
        }
        __syncthreads();

        f32x4 acc[3] = {};
        const size_t wrow0 = (size_t)(wc * 48 + l15) * D_MODEL;

        short8 bA[3][2], bB[3][2];
        #pragma unroll
        for (int ni = 0; ni < 3; ++ni) {
            const size_t base = wrow0 + (size_t)ni * 16 * D_MODEL;
            bA[ni][0] = *(const short8*)(Wt + base + g * 8);
            bA[ni][1] = *(const short8*)(Wt + base + 32 + g * 8);
        }

        auto gbody = [&](int t, short8 (&bcur)[3][2], short8 (&bnxt)[3][2]) {
            const int k0 = t * 64;
            if (t + 1 < 16) {
                #pragma unroll
                for (int ni = 0; ni < 3; ++ni) {
                    const size_t base = wrow0 + (size_t)ni * 16 * D_MODEL + k0 + 64;
                    bnxt[ni][0] = *(const short8*)(Wt + base + g * 8);
                    bnxt[ni][1] = *(const short8*)(Wt + base + 32 + g * 8);
                }
            }
            short8 af0 = *(const short8*)&sm.bp.Xs[(wr * 16 + l15) * 1032 + k0 + g * 8];
            short8 af1 = *(const short8*)&sm.bp.Xs[(wr * 16 + l15) * 1032 + k0 + 32 + g * 8];
            #pragma unroll
            for (int ni = 0; ni < 3; ++ni) {
                acc[ni] = __builtin_amdgcn_mfma_f32_16x16x32_bf16(af0, bcur[ni][0], acc[ni], 0, 0, 0);
                acc[ni] = __builtin_amdgcn_mfma_f32_16x16x32_bf16(af1, bcur[ni][1], acc[ni], 0, 0, 0);
            }
        };

        #pragma unroll 1
        for (int t = 0; t < 16; t += 2) {
            gbody(t,     bA, bB);
            gbody(t + 1, bB, bA);
        }

        // ---- epilogue: bias, q/k bf16, v -> LDS ----
        #pragma unroll
        for (int ni = 0; ni < 3; ++ni) {
            const int col = wc * 48 + ni * 16 + l15;
            const int mat = col >> 6, mc = col & 63;
            const float bias = (mat == 0 ? bq : (mat == 1 ? bk : bv))[mc];
            #pragma unroll
            for (int r = 0; r < 4; ++r) {
                const int rl = wr * 16 + g * 4 + r;
                const float val = acc[ni][r] + bias;
                if (mat == 0)      qb[(size_t)(row0 + rl) * HEAD + mc] = f2bf(val * 0.125f);
                else if (mat == 1) kb[(size_t)(row0 + rl) * HEAD + mc] = f2bf(val);
                else               sm.bp.Vx[rl][mc] = val;
            }
        }
        __syncthreads();

        // ---- transposed V store: vt[b][d][kv] ----
        {
            const int d = tid >> 3, kvc = (tid & 7) * 4;
            short4v o;
            #pragma unroll
            for (int j = 0; j < 4; ++j) o[j] = f2bf(sm.bp.Vx[kvc + j][d]);
            const int bb = row0 >> 11, kvloc = row0 & 2047;
            *(short4v*)(vt + ((size_t)bb * HEAD + d) * SEQ + kvloc + kvc) = o;
        }
    }

    grid.sync();

    // ===================== Phase C: causal flash attention =================
    {
        const int b = bx >> 6;
        const int p = bx & 63;

        const unsigned short* qg = qb + (size_t)b * SEQ * HEAD;
        const unsigned short* kg = kb + (size_t)b * SEQ * HEAD;
        const unsigned short* vg = vt + (size_t)b * HEAD * SEQ;

        #pragma unroll 1
        for (int half = 0; half < 2; ++half) {
            const int j     = half ? (127 - p) : p;
            const int q0    = j * 16;
            const int iters = (q0 + 16 + 255) >> 8;     // 256 kv / iteration

            // ---- stage Q tile ----
            if (tid < 128) {
                const int row = tid >> 3, slot = tid & 7;
                *(short8*)&sm.c.Qs[row * 68 + slot * 8] =
                    *(const short8*)(qg + (size_t)(q0 + row) * HEAD + slot * 8);
            }
            __syncthreads();

            const short8 qf0 = *(const short8*)&sm.c.Qs[l15 * 68 + g * 8];
            const short8 qf1 = *(const short8*)&sm.c.Qs[l15 * 68 + 32 + g * 8];

            float m_w = -1.0e30f, l_w = 0.0f;
            f32x4 acc[4] = {};

            // ---- prologue: K + V fragments for iter 0 ----
            short8 kA[4], kB2[4], vA[4], vB[4];
            #pragma unroll
            for (int u = 0; u < 4; ++u) {
                const int f = u >> 1, ks = u & 1;
                kA[u] = *(const short8*)(
                    kg + (size_t)(w * 32 + f * 16 + l15) * HEAD + ks * 32 + g * 8);
                vA[u] = *(const short8*)(
                    vg + (size_t)(u * 16 + l15) * SEQ + w * 32 + g * 8);
            }

            auto body = [&](int it, short8 (&kcur)[4], short8 (&knxt)[4],
                                    short8 (&vcur)[4], short8 (&vnxt)[4]) {
                const int kv0 = it * 256;

                // prefetch K+V for next iteration
                if (it + 1 < iters) {
                    #pragma unroll
                    for (int u = 0; u < 4; ++u) {
                        const int f = u >> 1, ks = u & 1;
                        knxt[u] = *(const short8*)(
                            kg + (size_t)(kv0 + 256 + w * 32 + f * 16 + l15) * HEAD
                               + ks * 32 + g * 8);
                        vnxt[u] = *(const short8*)(
                            vg + (size_t)(u * 16 + l15) * SEQ + kv0 + 256 + w * 32 + g * 8);
                    }
                }

                // ---- QK^T (swapped): S^T[kv 32][q 16] ----
                f32x4 sA[2] = {};
                sA[0] = __builtin_amdgcn_mfma_f32_16x16x32_bf16(kcur[0], qf0, sA[0], 0, 0, 0);
                sA[0] = __builtin_amdgcn_mfma_f32_16x16x32_bf16(kcur[1], qf1, sA[0], 0, 0, 0);
                sA[1] = __builtin_amdgcn_mfma_f32_16x16x32_bf16(kcur[2], qf0, sA[1], 0, 0, 0);
                sA[1] = __builtin_amdgcn_mfma_f32_16x16x32_bf16(kcur[3], qf1, sA[1], 0, 0, 0);

                // ---- causal mask (only last iteration crosses diagonal) ----
                if (it == iters - 1) {
                    const int kvb = kv0 + w * 32 + g * 4;
                    const int qq  = q0 + l15;
                    #pragma unroll
                    for (int f = 0; f < 2; ++f)
                        #pragma unroll
                        for (int r = 0; r < 4; ++r)
                            if (kvb + f * 16 + r > qq) sA[f][r] = -1.0e30f;
                }

                // ---- per-wave online softmax ----
                float smax = sA[0][0];
                #pragma unroll
                for (int r = 1; r < 4; ++r) smax = fmaxf(smax, sA[0][r]);
                #pragma unroll
                for (int r = 0; r < 4; ++r) smax = fmaxf(smax, sA[1][r]);
                smax = fmaxf(smax, __shfl_xor(smax, 16));
                smax = fmaxf(smax, __shfl_xor(smax, 32));

                const float mnew = fmaxf(m_w, smax);
                const float corr = __expf(m_w - mnew);
                float pv[8], psum = 0.0f;
                #pragma unroll
                for (int f = 0; f < 2; ++f)
                    #pragma unroll
                    for (int r = 0; r < 4; ++r) {
                        pv[f * 4 + r] = __expf(sA[f][r] - mnew);
                        psum += pv[f * 4 + r];
                    }
                psum += __shfl_xor(psum, 16);
                psum += __shfl_xor(psum, 32);
                l_w = l_w * corr + psum;
                m_w = mnew;

                // ---- pack P via wave-private LDS (no barrier) ----
                #pragma unroll
                for (int f = 0; f < 2; ++f) {
                    short4v pk;
                    pk[0] = f2bf(pv[f*4+0]); pk[1] = f2bf(pv[f*4+1]);
                    pk[2] = f2bf(pv[f*4+2]); pk[3] = f2bf(pv[f*4+3]);
                    *(short4v*)&sm.c.Ps[w][l15 * 40 + f * 16 + g * 4] = pk;
                }

                // ---- rescale acc ----
                float cf[4];
                #pragma unroll
                for (int r = 0; r < 4; ++r) cf[r] = __shfl(corr, g * 4 + r);
                #pragma unroll
                for (int ni = 0; ni < 4; ++ni)
                    #pragma unroll
                    for (int r = 0; r < 4; ++r) acc[ni][r] *= cf[r];

                // ---- PV ----
                const short8 pf = *(const short8*)&sm.c.Ps[w][l15 * 40 + g * 8];
                acc[0] = __builtin_amdgcn_mfma_f32_16x16x32_bf16(pf, vcur[0], acc[0], 0, 0, 0);
                acc[1] = __builtin_amdgcn_mfma_f32_16x16x32_bf16(pf, vcur[1], acc[1], 0, 0, 0);
                acc[2] = __builtin_amdgcn_mfma_f32_16x16x32_bf16(pf, vcur[2], acc[2], 0, 0, 0);
                acc[3] = __builtin_amdgcn_mfma_f32_16x16x32_bf16(pf, vcur[3], acc[3], 0, 0, 0);
            };

            #pragma unroll 1
            for (int itp = 0; itp < iters; itp += 2) {
                body(itp, kA, kB2, vA, vB);
                if (itp + 1 < iters) body(itp + 1, kB2, kA, vB, vA);
            }

            // ---- merge 8 wave-partials ----
            if (lane < 16) { sm.c.Sm[w * 16 + lane] = m_w; sm.c.Sl[w * 16 + lane] = l_w; }
            #pragma unroll
            for (int ni = 0; ni < 4; ++ni)
                #pragma unroll
                for (int r = 0; r < 4; ++r)
                    sm.c.Cs[w][(g * 4 + r) * 68 + ni * 16 + l15] = acc[ni][r];
            __syncthreads();

            if (tid < 256) {
                const int q = tid >> 4, d4 = (tid & 15) * 4;
                float mg = sm.c.Sm[q];
                #pragma unroll
                for (int ww = 1; ww < 8; ++ww) mg = fmaxf(mg, sm.c.Sm[ww * 16 + q]);
                f32x4 o = {0.f, 0.f, 0.f, 0.f};
                float lt = 0.0f;
                #pragma unroll
                for (int ww = 0; ww < 8; ++ww) {
                    const float f = __expf(sm.c.Sm[ww * 16 + q] - mg);
                    lt += sm.c.Sl[ww * 16 + q] * f;
                    f32x4 c4 = *(const f32x4*)&sm.c.Cs[ww][q * 68 + d4];
                    o[0] += c4[0] * f; o[1] += c4[1] * f;
                    o[2] += c4[2] * f; o[3] += c4[3] * f;
                }
                const float inv = 1.0f / lt;
                f32x4 res = {o[0]*inv, o[1]*inv, o[2]*inv, o[3]*inv};
                *(f32x4*)(out + ((size_t)b * SEQ + q0 + q) * HEAD + d4) = res;
            }
            __syncthreads();
        }
    }
}

// ---------------------------------------------------------------------------
extern "C" void kernel_launch(void* const* d_in, const int* in_sizes, int n_in,
                              void* d_out, int out_size, void* d_ws, size_t ws_size,
                              hipStream_t stream) {
    const float* x  = (const float*)d_in[0];
    const float* Wq = (const float*)d_in[1];
    const float* bq = (const float*)d_in[2];
    const float* Wk = (const float*)d_in[3];
    const float* bk = (const float*)d_in[4];
    const float* Wv = (const float*)d_in[5];
    const float* bv = (const float*)d_in[6];

    unsigned short* Wt  = (unsigned short*)d_ws;                  // 384 KB
    unsigned short* qbp = Wt + (size_t)192 * D_MODEL;             // 1 MB
    unsigned short* kbp = qbp + (size_t)ROWS * HEAD;              // 1 MB
    unsigned short* vtp = kbp + (size_t)ROWS * HEAD;              // 1 MB (V^T)
    float* o = (float*)d_out;

    void* args[] = { (void*)&x, (void*)&Wq, (void*)&bq, (void*)&Wk, (void*)&bk,
                     (void*)&Wv, (void*)&bv, (void*)&Wt, (void*)&qbp, (void*)&kbp,
                     (void*)&vtp, (void*)&o };
    hipLaunchCooperativeKernel((const void*)fused_all, dim3(256), dim3(512),
                               args, 0, stream);
}

// Round 9
// 134.016 us; speedup vs baseline: 1.4796x; 1.4796x over previous
//
#include <hip/hip_runtime.h>
#include <hip/hip_bf16.h>

#define D_MODEL 1024
#define HEAD    64
#define SEQ     2048
#define BATCH   4
#define ROWS    (BATCH * SEQ)   // 8192

typedef __attribute__((ext_vector_type(8))) short  short8;   // 8 bf16
typedef __attribute__((ext_vector_type(4))) short  short4v;  // 4 bf16
typedef __attribute__((ext_vector_type(4))) float  f32x4;

__device__ __forceinline__ unsigned short f2bf(float f) {
    union { __hip_bfloat16 h; unsigned short u; } c;
    c.h = __float2bfloat16(f);
    return c.u;
}

// ---------------------------------------------------------------------------
// Kernel 0: W[1024][64] f32 -> Wt[192][1024] bf16 (transposed, q|k|v concat).
// (R7-proven, unchanged)
// ---------------------------------------------------------------------------
__global__ __launch_bounds__(256) void conv_w(
    const float* __restrict__ Wq, const float* __restrict__ Wk,
    const float* __restrict__ Wv, unsigned short* __restrict__ Wt)
{
    __shared__ float Lw[64][65];
    const int tid = threadIdx.x;
    const int mat = blockIdx.x >> 4;
    const int k0  = (blockIdx.x & 15) * 64;
    const float* W = (mat == 0) ? Wq : (mat == 1 ? Wk : Wv);

    #pragma unroll
    for (int j = 0; j < 4; ++j) {
        const int idx = j * 1024 + tid * 4;
        const int r = idx >> 6, c = idx & 63;
        f32x4 v4 = *(const f32x4*)(W + (size_t)(k0 + r) * HEAD + c);
        Lw[r][c] = v4[0]; Lw[r][c+1] = v4[1]; Lw[r][c+2] = v4[2]; Lw[r][c+3] = v4[3];
    }
    __syncthreads();

    const int col = tid >> 2, kc = (tid & 3) * 16;
    short8 o0, o1;
    #pragma unroll
    for (int j = 0; j < 8; ++j) o0[j] = f2bf(Lw[kc + j][col]);
    #pragma unroll
    for (int j = 0; j < 8; ++j) o1[j] = f2bf(Lw[kc + 8 + j][col]);
    unsigned short* dst = Wt + (size_t)(mat * 64 + col) * D_MODEL + k0 + kc;
    *(short8*)(dst)     = o0;
    *(short8*)(dst + 8) = o1;
}

// ---------------------------------------------------------------------------
// Kernel 1: MFMA bf16 GEMM  C[8192][192] = x . Wt^T + b. (R7-proven, unchanged)
// ---------------------------------------------------------------------------
__global__ __launch_bounds__(256) void gemm_qkv(
    const float* __restrict__ x, const unsigned short* __restrict__ Wt,
    const float* __restrict__ bq, const float* __restrict__ bk,
    const float* __restrict__ bv,
    unsigned short* __restrict__ qb, unsigned short* __restrict__ kb,
    unsigned short* __restrict__ vt)
{
    __shared__ unsigned short Xs[16 * 1032];     // 33 KB
    __shared__ float Vx[16][66];

    const int tid  = threadIdx.x;
    const int lane = tid & 63;
    const int w    = tid >> 6;
    const int l15  = lane & 15;
    const int g    = lane >> 4;
    const int row0 = blockIdx.x * 16;

    {
        const int xrow  = tid >> 4;
        const int cbase = (tid & 15) * 4;
        #pragma unroll
        for (int j = 0; j < 16; ++j) {
            const int col = j * 64 + cbase;
            f32x4 v4 = *(const f32x4*)(x + (size_t)(row0 + xrow) * D_MODEL + col);
            short4v pk;
            pk[0] = f2bf(v4[0]); pk[1] = f2bf(v4[1]);
            pk[2] = f2bf(v4[2]); pk[3] = f2bf(v4[3]);
            *(short4v*)&Xs[xrow * 1032 + col] = pk;
        }
    }
    __syncthreads();

    f32x4 acc[3] = {};
    const size_t wrow0 = (size_t)(w * 48 + l15) * D_MODEL;

    short8 bA[3][2], bB[3][2];
    #pragma unroll
    for (int ni = 0; ni < 3; ++ni) {
        bA[ni][0] = *(const short8*)(Wt + wrow0 + (size_t)ni * 16 * D_MODEL + g * 8);
        bA[ni][1] = *(const short8*)(Wt + wrow0 + (size_t)ni * 16 * D_MODEL + 32 + g * 8);
    }

    auto gbody = [&](int t, short8 (&bcur)[3][2], short8 (&bnxt)[3][2]) {
        const int k0 = t * 64;
        if (t + 1 < 16) {
            #pragma unroll
            for (int ni = 0; ni < 3; ++ni) {
                const size_t base = wrow0 + (size_t)ni * 16 * D_MODEL + k0 + 64;
                bnxt[ni][0] = *(const short8*)(Wt + base + g * 8);
                bnxt[ni][1] = *(const short8*)(Wt + base + 32 + g * 8);
            }
        }
        short8 af0 = *(const short8*)&Xs[l15 * 1032 + k0 + g * 8];
        short8 af1 = *(const short8*)&Xs[l15 * 1032 + k0 + 32 + g * 8];
        #pragma unroll
        for (int ni = 0; ni < 3; ++ni) {
            acc[ni] = __builtin_amdgcn_mfma_f32_16x16x32_bf16(af0, bcur[ni][0], acc[ni], 0, 0, 0);
            acc[ni] = __builtin_amdgcn_mfma_f32_16x16x32_bf16(af1, bcur[ni][1], acc[ni], 0, 0, 0);
        }
    };

    #pragma unroll 1
    for (int t = 0; t < 16; t += 2) {
        gbody(t,     bA, bB);
        gbody(t + 1, bB, bA);
    }

    #pragma unroll
    for (int ni = 0; ni < 3; ++ni) {
        const int col = w * 48 + ni * 16 + l15;
        const int mat = col >> 6, mc = col & 63;
        const float bias = (mat == 0 ? bq : (mat == 1 ? bk : bv))[mc];
        #pragma unroll
        for (int r = 0; r < 4; ++r) {
            const int rl = g * 4 + r;
            const float val = acc[ni][r] + bias;
            if (mat == 0)      qb[(size_t)(row0 + rl) * HEAD + mc] = f2bf(val * 0.125f);
            else if (mat == 1) kb[(size_t)(row0 + rl) * HEAD + mc] = f2bf(val);
            else               Vx[rl][mc] = val;
        }
    }
    __syncthreads();

    {
        const int d = tid >> 2, kvc = (tid & 3) * 4;
        short4v o;
        #pragma unroll
        for (int j = 0; j < 4; ++j) o[j] = f2bf(Vx[kvc + j][d]);
        const int bb = row0 >> 11, kvloc = row0 & 2047;
        *(short4v*)(vt + ((size_t)bb * HEAD + d) * SEQ + kvloc + kvc) = o;
    }
}

// ---------------------------------------------------------------------------
// Kernel 2: causal flash attention, partitioned (flash-decoding).
// Grid (320, 4) x 256 thr. Task t -> (q-tile j, kv-chunk c of <=512):
//   t<32: j=t,c=0,nch=1 | t<96: j=32+(t-32)/2 | t<192: j=64+(t-96)/3 |
//   else: j=96+(t-192)/4.  Wave w owns interleaved 32-kv blocks
//   kv0 = c*512 + w*32 + s*128 (s<4).  O^T accumulation: acc=mfma(V^T,P)
//   puts q on lane&15 -> corr/l applied per-lane, NO rescale shuffles.
//   In-block merge of 4 wave partials; nch==1 writes out, else partial to ws.
// ---------------------------------------------------------------------------
__global__ __launch_bounds__(256, 4) void attn_part(
    const unsigned short* __restrict__ qb, const unsigned short* __restrict__ kb,
    const unsigned short* __restrict__ vt, float* __restrict__ out,
    float* __restrict__ pws)
{
    __shared__ unsigned short Qs[16 * 68];       // 2.2 KB
    __shared__ unsigned short Ps[4][16 * 40];    // 5 KB
    __shared__ float Cs[4][16 * 68];             // 17.4 KB
    __shared__ float Sm[64], Sl[64];

    const int tid  = threadIdx.x;
    const int lane = tid & 63;
    const int w    = tid >> 6;        // 0..3
    const int l15  = lane & 15;
    const int g    = lane >> 4;
    const int t    = blockIdx.x;      // 0..319
    const int b    = blockIdx.y;

    int j, c, nch;
    if (t < 32)       { j = t;                  c = 0;             nch = 1; }
    else if (t < 96)  { int u = t - 32;  j = 32 + (u >> 1); c = u & 1;         nch = 2; }
    else if (t < 192) { int u = t - 96;  j = 64 + u / 3;    c = u - (u / 3) * 3; nch = 3; }
    else              { int u = t - 192; j = 96 + (u >> 2); c = u & 3;         nch = 4; }

    const int q0    = j * 16;
    const int kv_lo = c * 512;
    const int kv_hi = min(kv_lo + 512, q0 + 16);

    const unsigned short* qg = qb + (size_t)b * SEQ * HEAD;
    const unsigned short* kg = kb + (size_t)b * SEQ * HEAD;
    const unsigned short* vg = vt + (size_t)b * HEAD * SEQ;

    // ---- stage Q tile ----
    if (tid < 128) {
        const int row = tid >> 3, slot = tid & 7;
        *(short8*)&Qs[row * 68 + slot * 8] =
            *(const short8*)(qg + (size_t)(q0 + row) * HEAD + slot * 8);
    }
    __syncthreads();

    const short8 qf0 = *(const short8*)&Qs[l15 * 68 + g * 8];
    const short8 qf1 = *(const short8*)&Qs[l15 * 68 + 32 + g * 8];

    float m_w = -1.0e30f, l_w = 0.0f;
    f32x4 acc[4] = {};

    const int lo_w = kv_lo + w * 32;                       // wave's first 32-block
    const int ns   = (kv_hi > lo_w) ? min(4, (kv_hi - lo_w + 127) >> 7) : 0;
    const int qq   = q0 + l15;                             // this lane's q

    auto body = [&](int s, short8 (&kcur)[4], short8 (&knxt)[4]) {
        const int kv0 = lo_w + s * 128;

        // V fragments for current sub-iter (consumed after softmax ~400cy later)
        short8 vc0, vc1, vc2, vc3;
        {
            const size_t vbs = (size_t)l15 * SEQ + kv0 + g * 8;
            vc0 = *(const short8*)(vg + vbs);
            vc1 = *(const short8*)(vg + vbs + (size_t)16 * SEQ);
            vc2 = *(const short8*)(vg + vbs + (size_t)32 * SEQ);
            vc3 = *(const short8*)(vg + vbs + (size_t)48 * SEQ);
        }

        // K prefetch for next sub-iter
        if (s + 1 < ns) {
            #pragma unroll
            for (int u = 0; u < 4; ++u) {
                const int f = u >> 1, ks = u & 1;
                knxt[u] = *(const short8*)(
                    kg + (size_t)(kv0 + 128 + f * 16 + l15) * HEAD + ks * 32 + g * 8);
            }
        }

        // ---- QK^T (swapped): S^T[kv 32][q 16] ----
        f32x4 sA[2] = {};
        sA[0] = __builtin_amdgcn_mfma_f32_16x16x32_bf16(kcur[0], qf0, sA[0], 0, 0, 0);
        sA[0] = __builtin_amdgcn_mfma_f32_16x16x32_bf16(kcur[1], qf1, sA[0], 0, 0, 0);
        sA[1] = __builtin_amdgcn_mfma_f32_16x16x32_bf16(kcur[2], qf0, sA[1], 0, 0, 0);
        sA[1] = __builtin_amdgcn_mfma_f32_16x16x32_bf16(kcur[3], qf1, sA[1], 0, 0, 0);

        // ---- causal mask (only sub-iters that can cross the diagonal) ----
        if (kv0 + 32 > q0) {
            const int kvb = kv0 + g * 4;
            #pragma unroll
            for (int f = 0; f < 2; ++f)
                #pragma unroll
                for (int r = 0; r < 4; ++r)
                    if (kvb + f * 16 + r > qq) sA[f][r] = -1.0e30f;
        }

        // ---- per-wave online softmax (q = l15, copies over g) ----
        float smax = sA[0][0];
        #pragma unroll
        for (int r = 1; r < 4; ++r) smax = fmaxf(smax, sA[0][r]);
        #pragma unroll
        for (int r = 0; r < 4; ++r) smax = fmaxf(smax, sA[1][r]);
        smax = fmaxf(smax, __shfl_xor(smax, 16));
        smax = fmaxf(smax, __shfl_xor(smax, 32));

        const float mnew = fmaxf(m_w, smax);
        const float corr = __expf(m_w - mnew);
        float pv[8], psum = 0.0f;
        #pragma unroll
        for (int f = 0; f < 2; ++f)
            #pragma unroll
            for (int r = 0; r < 4; ++r) {
                pv[f * 4 + r] = __expf(sA[f][r] - mnew);
                psum += pv[f * 4 + r];
            }
        psum += __shfl_xor(psum, 16);
        psum += __shfl_xor(psum, 32);
        l_w = l_w * corr + psum;
        m_w = mnew;

        // ---- pack P via wave-private LDS (no barrier) ----
        #pragma unroll
        for (int f = 0; f < 2; ++f) {
            short4v pk;
            pk[0] = f2bf(pv[f*4+0]); pk[1] = f2bf(pv[f*4+1]);
            pk[2] = f2bf(pv[f*4+2]); pk[3] = f2bf(pv[f*4+3]);
            *(short4v*)&Ps[w][l15 * 40 + f * 16 + g * 4] = pk;
        }

        // ---- rescale acc: corr is per-q = per-lane (O^T layout) ----
        #pragma unroll
        for (int ni = 0; ni < 4; ++ni)
            #pragma unroll
            for (int r = 0; r < 4; ++r) acc[ni][r] *= corr;

        // ---- PV, operand-swapped: O^T[d][q] += V^T . P ----
        const short8 pf = *(const short8*)&Ps[w][l15 * 40 + g * 8];
        acc[0] = __builtin_amdgcn_mfma_f32_16x16x32_bf16(vc0, pf, acc[0], 0, 0, 0);
        acc[1] = __builtin_amdgcn_mfma_f32_16x16x32_bf16(vc1, pf, acc[1], 0, 0, 0);
        acc[2] = __builtin_amdgcn_mfma_f32_16x16x32_bf16(vc2, pf, acc[2], 0, 0, 0);
        acc[3] = __builtin_amdgcn_mfma_f32_16x16x32_bf16(vc3, pf, acc[3], 0, 0, 0);
    };

    if (ns > 0) {
        short8 kA[4], kB2[4];
        #pragma unroll
        for (int u = 0; u < 4; ++u) {
            const int f = u >> 1, ks = u & 1;
            kA[u] = *(const short8*)(
                kg + (size_t)(lo_w + f * 16 + l15) * HEAD + ks * 32 + g * 8);
        }
        body(0, kA, kB2);
        if (ns > 1) body(1, kB2, kA);
        if (ns > 2) body(2, kA, kB2);
        if (ns > 3) body(3, kB2, kA);
    }

    // ---- in-block merge of 4 wave-partials ----
    if (lane < 16) { Sm[w * 16 + lane] = m_w; Sl[w * 16 + lane] = l_w; }
    #pragma unroll
    for (int ni = 0; ni < 4; ++ni)
        *(f32x4*)&Cs[w][l15 * 68 + ni * 16 + g * 4] = acc[ni];   // [q][d]
    __syncthreads();

    {
        const int q = tid >> 4, d4 = (tid & 15) * 4;
        float mg = Sm[q];
        #pragma unroll
        for (int ww = 1; ww < 4; ++ww) mg = fmaxf(mg, Sm[ww * 16 + q]);
        f32x4 o = {0.f, 0.f, 0.f, 0.f};
        float lt = 0.0f;
        #pragma unroll
        for (int ww = 0; ww < 4; ++ww) {
            const float f = __expf(Sm[ww * 16 + q] - mg);
            lt += Sl[ww * 16 + q] * f;
            f32x4 c4 = *(const f32x4*)&Cs[ww][q * 68 + d4];
            o[0] += c4[0] * f; o[1] += c4[1] * f;
            o[2] += c4[2] * f; o[3] += c4[3] * f;
        }
        if (nch == 1) {
            const float inv = 1.0f / lt;
            f32x4 res = {o[0]*inv, o[1]*inv, o[2]*inv, o[3]*inv};
            *(f32x4*)(out + ((size_t)b * SEQ + q0 + q) * HEAD + d4) = res;
        } else {
            float* pp = pws + (size_t)((b * 128 + j) * 4 + c) * 1056;
            *(f32x4*)(pp + q * 64 + d4) = o;                  // unnormalized
            if ((tid & 15) == 0) { pp[1024 + q] = mg; pp[1040 + q] = lt; }
        }
    }
}

// ---------------------------------------------------------------------------
// Kernel 3: combine kv-chunk partials for q-tiles j>=32.  Grid (96,4) x 256.
// ---------------------------------------------------------------------------
__global__ __launch_bounds__(256) void attn_reduce(
    const float* __restrict__ pws, float* __restrict__ out)
{
    const int jj  = 32 + blockIdx.x;          // 32..127
    const int b   = blockIdx.y;
    const int nch = (jj >> 5) + 1;            // 2..4
    const int q   = threadIdx.x >> 4;
    const int d4  = (threadIdx.x & 15) * 4;

    const float* p0 = pws + (size_t)((b * 128 + jj) * 4) * 1056;

    float mg = -1.0e30f;
    for (int cc = 0; cc < nch; ++cc)
        mg = fmaxf(mg, p0[(size_t)cc * 1056 + 1024 + q]);

    f32x4 o = {0.f, 0.f, 0.f, 0.f};
    float lt = 0.0f;
    for (int cc = 0; cc < nch; ++cc) {
        const float* pc = p0 + (size_t)cc * 1056;
        const float f = __expf(pc[1024 + q] - mg);
        lt += pc[1040 + q] * f;
        f32x4 a4 = *(const f32x4*)(pc + q * 64 + d4);
        o[0] += a4[0] * f; o[1] += a4[1] * f;
        o[2] += a4[2] * f; o[3] += a4[3] * f;
    }
    const float inv = 1.0f / lt;
    f32x4 res = {o[0]*inv, o[1]*inv, o[2]*inv, o[3]*inv};
    *(f32x4*)(out + ((size_t)b * SEQ + jj * 16 + q) * HEAD + d4) = res;
}

// ---------------------------------------------------------------------------
extern "C" void kernel_launch(void* const* d_in, const int* in_sizes, int n_in,
                              void* d_out, int out_size, void* d_ws, size_t ws_size,
                              hipStream_t stream) {
    const float* x  = (const float*)d_in[0];
    const float* Wq = (const float*)d_in[1];
    const float* bq = (const float*)d_in[2];
    const float* Wk = (const float*)d_in[3];
    const float* bk = (const float*)d_in[4];
    const float* Wv = (const float*)d_in[5];
    const float* bv = (const float*)d_in[6];

    unsigned short* Wt  = (unsigned short*)d_ws;                  // 384 KB
    unsigned short* qbp = Wt + (size_t)192 * D_MODEL;             // 1 MB
    unsigned short* kbp = qbp + (size_t)ROWS * HEAD;              // 1 MB
    unsigned short* vtp = kbp + (size_t)ROWS * HEAD;              // 1 MB (V^T)
    float*          pws = (float*)(vtp + (size_t)ROWS * HEAD);    // 8.65 MB
    float* o = (float*)d_out;

    conv_w     <<<dim3(48),       dim3(256), 0, stream>>>(Wq, Wk, Wv, Wt);
    gemm_qkv   <<<dim3(512),      dim3(256), 0, stream>>>(x, Wt, bq, bk, bv, qbp, kbp, vtp);
    attn_part  <<<dim3(320, 4),   dim3(256), 0, stream>>>(qbp, kbp, vtp, o, pws);
    attn_reduce<<<dim3(96, 4),    dim3(256), 0, stream>>>(pws, o);
}